// Round 12
// baseline (9784.574 us; speedup 1.0000x reference)
//
#include <hip/hip_runtime.h>
#include <math.h>

constexpr int   P      = 16;   // N_POINTS
constexpr int   DIN    = 48;   // P*3
constexpr int   DH     = 64;   // hidden dim
constexpr int   NITER  = 8;    // I
constexpr int   NLAYER = 2;    // L
constexpr float BIGV   = 1e9f;
constexpr float INV_R  = 1.0f / 2.5f;
constexpr int   RLOG   = 20;   // fast path requires R == 1<<20

typedef float f32x4  __attribute__((ext_vector_type(4)));
typedef short bf16x8 __attribute__((ext_vector_type(8)));

// Pre-packed B-fragments (bf16 hi/lo planes, fragment-ordered):
// layer L in {0:W_in, 1:W_mid0, 2:W_mid1}; frag fi = (kc*4+ni)*2+pl; 64 lanes x 16B.
__device__ __align__(16) unsigned g_blob[3 * 16 * 64 * 4];

// bf16 round-to-nearest-even helpers (pure arithmetic)
__device__ __forceinline__ unsigned bf16rne(float x) {
    unsigned b = __float_as_uint(x);
    return (b + 0x7FFFu + ((b >> 16) & 1u)) >> 16;
}
__device__ __forceinline__ float bf16tof(unsigned h) { return __uint_as_float(h << 16); }

union FragCvt { uint4 u; bf16x8 h; };
__device__ __forceinline__ bf16x8 tofrag(unsigned w0, unsigned w1, unsigned w2, unsigned w3) {
    FragCvt f; f.u = make_uint4(w0, w1, w2, w3); return f.h;
}
__device__ __forceinline__ bf16x8 tofrag4(uint4 u) { FragCvt f; f.u = u; return f.h; }

// monotonic float<->uint key map (total order)
__device__ __forceinline__ unsigned fkey(float f) {
    unsigned b = __float_as_uint(f);
    return (b & 0x80000000u) ? ~b : (b | 0x80000000u);
}
__device__ __forceinline__ float funkey(unsigned k) {
    unsigned b = (k & 0x80000000u) ? (k ^ 0x80000000u) : ~k;
    return __uint_as_float(b);
}

// ---------------------------------------------------------------------------
// SLOW PATH (rare): correctly-rounded f32 elementwise, f64 reductions.
// Verbatim from all passing rounds.
// ---------------------------------------------------------------------------
__device__ __noinline__
void slow_eval(const float* __restrict__ orig, const float* __restrict__ vec,
               const float* __restrict__ t1,   const float* __restrict__ t2,
               size_t tidx, unsigned r,
               const float* __restrict__ W_in,  const float* __restrict__ b_in,
               const float* __restrict__ ln_g,  const float* __restrict__ ln_b,
               const float* __restrict__ W_mid, const float* __restrict__ b_mid,
               const float* __restrict__ W_cls, const float* __restrict__ b_cls,
               const float* __restrict__ W_dist,const float* __restrict__ b_dist,
               float& cls_o, float& dval_o)
{
    const float o0 = orig[3*r+0], o1 = orig[3*r+1], o2 = orig[3*r+2];
    const float v0 = vec[3*r+0],  v1 = vec[3*r+1],  v2 = vec[3*r+2];
    const float t1i = t1[tidx], t2i = t2[tidx];

    const float dt  = __fsub_rn(t2i, t1i);
    const float io0 = __fadd_rn(o0, __fmul_rn(v0, t1i));
    const float io1 = __fadd_rn(o1, __fmul_rn(v1, t1i));
    const float io2 = __fadd_rn(o2, __fmul_rn(v2, t1i));
    const float iv0 = __fmul_rn(v0, dt);
    const float iv1 = __fmul_rn(v1, dt);
    const float iv2 = __fmul_rn(v2, dt);
    const float delta = 1.0f / 15.0f;

    float x[DIN];
    #pragma unroll
    for (int p = 0; p < P; ++p) {
        const float tp = __fmul_rn((float)p, delta);
        x[3*p+0] = __fdiv_rn(__fadd_rn(io0, __fmul_rn(iv0, tp)), 2.5f);
        x[3*p+1] = __fdiv_rn(__fadd_rn(io1, __fmul_rn(iv1, tp)), 2.5f);
        x[3*p+2] = __fdiv_rn(__fadd_rn(io2, __fmul_rn(iv2, tp)), 2.5f);
    }

    float a[DH];
    #pragma unroll 1
    for (int d = 0; d < DH; ++d) {
        double acc0 = 0.0, acc1 = 0.0;
        #pragma unroll
        for (int k = 0; k < DIN; k += 2) {
            acc0 = fma((double)x[k],   (double)W_in[k*DH + d],     acc0);
            acc1 = fma((double)x[k+1], (double)W_in[(k+1)*DH + d], acc1);
        }
        a[d] = __fadd_rn((float)(acc0 + acc1), b_in[d]);
    }

    #pragma unroll 1
    for (int l = 0; l < NLAYER; ++l) {
        #pragma unroll 1
        for (int d = 0; d < DH; ++d) a[d] = fmaxf(a[d], 0.0f);

        double s = 0.0;
        #pragma unroll 1
        for (int d = 0; d < DH; ++d) s += (double)a[d];
        const float mu = (float)(s * (1.0 / 64.0));

        double vs = 0.0;
        #pragma unroll 1
        for (int d = 0; d < DH; ++d) {
            const float c = __fsub_rn(a[d], mu);
            vs = fma((double)c, (double)c, vs);
        }
        const float var = (float)(vs * (1.0 / 64.0));
        const float ve  = __fadd_rn(var, 1e-5f);
        const float inv = (float)(1.0 / sqrt((double)ve));

        float hn[DH];
        #pragma unroll 1
        for (int d = 0; d < DH; ++d) {
            float t = __fsub_rn(a[d], mu);
            t = __fmul_rn(t, inv);
            t = __fmul_rn(t, ln_g[l*DH + d]);
            hn[d] = __fadd_rn(t, ln_b[l*DH + d]);
        }

        #pragma unroll 1
        for (int d = 0; d < DH; ++d) {
            double acc0 = 0.0, acc1 = 0.0;
            #pragma unroll
            for (int k = 0; k < DH; k += 2) {
                acc0 = fma((double)hn[k],   (double)W_mid[(l*DH + k)*DH + d],   acc0);
                acc1 = fma((double)hn[k+1], (double)W_mid[(l*DH + k+1)*DH + d], acc1);
            }
            a[d] = __fadd_rn((float)(acc0 + acc1), b_mid[l*DH + d]);
        }
    }

    double c0 = 0.0, c1 = 0.0, d0 = 0.0, d1 = 0.0;
    #pragma unroll 1
    for (int d = 0; d < DH; d += 2) {
        const float h0 = fmaxf(a[d],   0.0f);
        const float h1 = fmaxf(a[d+1], 0.0f);
        c0 = fma((double)h0, (double)W_cls[d],    c0);
        c1 = fma((double)h1, (double)W_cls[d+1],  c1);
        d0 = fma((double)h0, (double)W_dist[d],   d0);
        d1 = fma((double)h1, (double)W_dist[d+1], d1);
    }
    const float cls = __fadd_rn((float)(c0 + c1), b_cls[0]);
    const float dv  = __fadd_rn((float)(d0 + d1), b_dist[0]);
    cls_o  = cls;
    dval_o = __fadd_rn(__fmul_rn(dv, dt), t1i);
}

// ---------------------------------------------------------------------------
// Compaction / init / finalize (verbatim from passing rounds)
// ---------------------------------------------------------------------------
__global__ __launch_bounds__(256)
void compact_k(const int* __restrict__ mask, unsigned* __restrict__ cnt,
               unsigned* __restrict__ work)
{
    const int idx  = blockIdx.x * 256 + threadIdx.x;
    const int lane = threadIdx.x & 63;
    const bool m = (mask[idx] != 0);
    const unsigned long long b = __ballot(m);
    const int nact = __popcll(b);
    unsigned base = 0;
    if (lane == 0 && nact) base = atomicAdd(cnt, (unsigned)nact);
    base = __shfl(base, 0);
    if (m) {
        const int pre = __popcll(b & ((1ull << lane) - 1ull));
        work[base + pre] = (unsigned)idx;
    }
}

__global__ __launch_bounds__(256)
void init_k(unsigned* __restrict__ arena, int R)
{
    const unsigned key_big = fkey(BIGV);
    for (int r = blockIdx.x * 256 + threadIdx.x; r < R; r += gridDim.x * 256)
        arena[r] = key_big;
}

__global__ __launch_bounds__(256)
void finalize_k(float* __restrict__ out, int R)
{
    unsigned* arena = (unsigned*)out + R;
    for (int r = blockIdx.x * 256 + threadIdx.x; r < R; r += gridDim.x * 256) {
        const float dist = funkey(arena[r]);
        const float dfin = (dist == BIGV) ? 0.0f : dist;
        out[r] = (dfin > 0.0f) ? 1.0f : 0.0f;
        ((float*)arena)[r] = dfin;
    }
}

// ---------------------------------------------------------------------------
// Weight-fragment prep (verbatim, validated): pack W_in/W_mid as bf16 hi/lo
// B-fragments in mfma lane order (B: n = lane&15, k = (lane>>4)*8+e).
// ---------------------------------------------------------------------------
__global__ __launch_bounds__(256)
void prep_k(const float* __restrict__ W_in, const float* __restrict__ W_mid)
{
    const int id = blockIdx.x * 256 + threadIdx.x;
    if (id >= 3 * 4096) return;
    const int L    = id >> 12;         // 0:W_in 1:Wmid0 2:Wmid1
    const int fi   = (id >> 8) & 15;   // (kc*4+ni)*2+pl
    const int lane = (id >> 2) & 63;
    const int w    = id & 3;
    const int pl = fi & 1, ni = (fi >> 1) & 3, kc = fi >> 3;
    const int n  = ni * 16 + (lane & 15);
    const int k0 = kc * 32 + ((lane >> 4) << 3) + 2 * w;

    float v0, v1;
    if (L == 0) {
        v0 = (k0     < DIN) ? W_in[k0 * DH + n]       : 0.0f;
        v1 = (k0 + 1 < DIN) ? W_in[(k0 + 1) * DH + n] : 0.0f;
    } else {
        v0 = W_mid[(L - 1) * DH * DH + k0 * DH + n];
        v1 = W_mid[(L - 1) * DH * DH + (k0 + 1) * DH + n];
    }
    const unsigned h0 = bf16rne(v0), h1 = bf16rne(v1);
    unsigned outw;
    if (pl == 0) outw = h0 | (h1 << 16);
    else {
        const float l0 = v0 - bf16tof(h0), l1 = v1 - bf16tof(h1);
        outw = bf16rne(l0) | (bf16rne(l1) << 16);
    }
    g_blob[id] = outw;
}

// ---------------------------------------------------------------------------
// MAIN (MFMA, 32-item wave tile, 256-thread block): body validated in
// R10/R11 (absmax 0.0078). Empirical allocator law: 512-thread blocks are
// capped at 128 VGPR (5/5 data points) -> the acc spilled -> 250 MB scratch
// traffic = the entire runtime. 4-wave blocks with (256,1) got 192 VGPR
// (R6) -> live set (~110) fits, no spill. LDS Hb[4][32][68] = 34.8 KB ->
// >=2 blocks/CU. No barriers (per-wave LDS, same-wave DS in-order).
// C layout (HW-verified): d = ni*16+(lane&15), item = mi*16+(lane>>4)*4+reg.
// ---------------------------------------------------------------------------
__global__ __launch_bounds__(256, 1)
void mfma_k(const float* __restrict__ orig,
            const float* __restrict__ vec,
            const float* __restrict__ t1,
            const float* __restrict__ t2,
            const float* __restrict__ W_in,
            const float* __restrict__ b_in,
            const float* __restrict__ ln_g,
            const float* __restrict__ ln_b,
            const float* __restrict__ W_mid,
            const float* __restrict__ b_mid,
            const float* __restrict__ W_cls,
            const float* __restrict__ b_cls,
            const float* __restrict__ W_dist,
            const float* __restrict__ b_dist,
            const unsigned* __restrict__ work,
            const unsigned* __restrict__ cnt,
            unsigned* __restrict__ arena)
{
    __shared__ __align__(16) float Hb[4][32][68];   // 34.8 KiB, per-wave private

    const int tid  = threadIdx.x;
    const int lane = tid & 63;
    const int wv   = tid >> 6;          // 0..3
    const int l15  = lane & 15;
    const int g    = lane >> 4;

    float* Hw = &Hb[wv][0][0];
    const int wbase = g * 4 * 68 + l15;   // + mi*1088 + rr*68 + ni*16
    const int rbase = l15 * 68 + g * 8;   // + mi*1088 + kc*32 (+4)

    const unsigned T = *cnt;
    if (T == 0) return;
    const unsigned ntiles = (T + 31) >> 5;
    const unsigned wgid = blockIdx.x * 4 + wv;
    const unsigned nw   = gridDim.x * 4;
    const uint4* fragp = (const uint4*)g_blob;

    // tile-invariant per-lane constants
    float bin4[4], wc[4], wd[4];
    #pragma unroll
    for (int ni = 0; ni < 4; ++ni) {
        bin4[ni] = b_in[ni * 16 + l15];
        wc[ni]   = W_cls[ni * 16 + l15];
        wd[ni]   = W_dist[ni * 16 + l15];
    }
    const float bcls = b_cls[0], bdst = b_dist[0];

    #pragma unroll 1
    for (unsigned tile = wgid; tile < ntiles; tile += nw) {
        const unsigned base = tile << 5;

        // ---- per-mi item meta (lane handles item mi*16 + l15)
        float io[2][3], iv[2][3];
        #pragma unroll
        for (int mi = 0; mi < 2; ++mi) {
            unsigned idx = base + mi * 16 + l15;
            if (idx >= T) idx = T - 1;
            const unsigned pk = work[idx];
            const unsigned r  = pk & 0xFFFFFu;
            const float tt1 = t1[pk], tt2 = t2[pk];
            const float dt = tt2 - tt1;
            const float o0 = orig[3*r+0], o1 = orig[3*r+1], o2 = orig[3*r+2];
            const float v0 = vec[3*r+0],  v1 = vec[3*r+1],  v2 = vec[3*r+2];
            io[mi][0] = fmaf(v0, tt1, o0);
            io[mi][1] = fmaf(v1, tt1, o1);
            io[mi][2] = fmaf(v2, tt1, o2);
            iv[mi][0] = v0 * dt; iv[mi][1] = v1 * dt; iv[mi][2] = v2 * dt;
        }

        f32x4 c[2][4];
        #pragma unroll
        for (int mi = 0; mi < 2; ++mi)
            #pragma unroll
            for (int ni = 0; ni < 4; ++ni)
                c[mi][ni] = f32x4{0.f, 0.f, 0.f, 0.f};

        // ---- input layer: A built in-registers; B frags from blob (L=0)
        #pragma unroll
        for (int kc = 0; kc < 2; ++kc) {
            bf16x8 ahi[2], alo[2];
            #pragma unroll
            for (int mi = 0; mi < 2; ++mi) {
                unsigned hw[4], lw[4];
                #pragma unroll
                for (int w = 0; w < 4; ++w) {
                    float xv[2];
                    #pragma unroll
                    for (int s = 0; s < 2; ++s) {
                        const int e = 2 * w + s;
                        const int k = kc * 32 + g * 8 + e;
                        const unsigned ku = (unsigned)k;
                        const unsigned p  = ku / 3u;
                        const unsigned cm = ku - 3u * p;
                        const float tp = (float)p * (1.0f / 15.0f);
                        const float ios = cm == 0 ? io[mi][0] : (cm == 1 ? io[mi][1] : io[mi][2]);
                        const float ivs = cm == 0 ? iv[mi][0] : (cm == 1 ? iv[mi][1] : iv[mi][2]);
                        float x = fmaf(ivs, tp, ios) * INV_R;
                        xv[s] = (k < DIN) ? x : 0.0f;
                    }
                    const unsigned h0 = bf16rne(xv[0]), h1 = bf16rne(xv[1]);
                    hw[w] = h0 | (h1 << 16);
                    const float l0 = xv[0] - bf16tof(h0), l1 = xv[1] - bf16tof(h1);
                    lw[w] = bf16rne(l0) | (bf16rne(l1) << 16);
                }
                ahi[mi] = tofrag(hw[0], hw[1], hw[2], hw[3]);
                alo[mi] = tofrag(lw[0], lw[1], lw[2], lw[3]);
            }
            #pragma unroll
            for (int ni = 0; ni < 4; ++ni) {
                const bf16x8 bhi = tofrag4(fragp[((kc * 4 + ni) * 2 + 0) * 64 + lane]);
                const bf16x8 blo = tofrag4(fragp[((kc * 4 + ni) * 2 + 1) * 64 + lane]);
                #pragma unroll
                for (int mi = 0; mi < 2; ++mi) {
                    c[mi][ni] = __builtin_amdgcn_mfma_f32_16x16x32_bf16(ahi[mi], bhi, c[mi][ni], 0, 0, 0);
                    c[mi][ni] = __builtin_amdgcn_mfma_f32_16x16x32_bf16(ahi[mi], blo, c[mi][ni], 0, 0, 0);
                    c[mi][ni] = __builtin_amdgcn_mfma_f32_16x16x32_bf16(alo[mi], bhi, c[mi][ni], 0, 0, 0);
                }
            }
        }
        #pragma unroll
        for (int ni = 0; ni < 4; ++ni)
            #pragma unroll
            for (int mi = 0; mi < 2; ++mi) {
                c[mi][ni][0] += bin4[ni]; c[mi][ni][1] += bin4[ni];
                c[mi][ni][2] += bin4[ni]; c[mi][ni][3] += bin4[ni];
            }

        float invp[2][4];
        #pragma unroll
        for (int mi = 0; mi < 2; ++mi)
            #pragma unroll
            for (int rr = 0; rr < 4; ++rr) invp[mi][rr] = 1.0f;

        // ---- mid layers
        #pragma unroll 1
        for (int l = 0; l < NLAYER; ++l) {
            #pragma unroll
            for (int mi = 0; mi < 2; ++mi)
                #pragma unroll
                for (int ni = 0; ni < 4; ++ni)
                    #pragma unroll
                    for (int rr = 0; rr < 4; ++rr)
                        c[mi][ni][rr] = fmaxf(c[mi][ni][rr], 0.0f);

            // LN stats per (mi,rr): reduce over ni-regs + 16-lane shfl
            float gg[4], bb[4];
            #pragma unroll
            for (int ni = 0; ni < 4; ++ni) {
                gg[ni] = ln_g[l * DH + ni * 16 + l15];
                bb[ni] = ln_b[l * DH + ni * 16 + l15];
            }
            #pragma unroll
            for (int mi = 0; mi < 2; ++mi)
                #pragma unroll
                for (int rr = 0; rr < 4; ++rr) {
                    float s = c[mi][0][rr] + c[mi][1][rr] + c[mi][2][rr] + c[mi][3][rr];
                    s += __shfl_xor(s, 1); s += __shfl_xor(s, 2);
                    s += __shfl_xor(s, 4); s += __shfl_xor(s, 8);
                    const float mu = s * (1.0f / 64.0f);
                    float vp = 0.0f;
                    #pragma unroll
                    for (int ni = 0; ni < 4; ++ni) {
                        const float d0 = c[mi][ni][rr] - mu;
                        vp = fmaf(d0, d0, vp);
                    }
                    vp += __shfl_xor(vp, 1); vp += __shfl_xor(vp, 2);
                    vp += __shfl_xor(vp, 4); vp += __shfl_xor(vp, 8);
                    const float var = vp * (1.0f / 64.0f);
                    const float inv = 1.0f / sqrtf(var + 1e-5f);
                    invp[mi][rr] *= inv;
                    #pragma unroll
                    for (int ni = 0; ni < 4; ++ni) {
                        const float t = (c[mi][ni][rr] - mu) * inv;
                        Hw[wbase + mi * 1088 + rr * 68 + ni * 16] = fmaf(t, gg[ni], bb[ni]);
                    }
                }

            #pragma unroll
            for (int mi = 0; mi < 2; ++mi)
                #pragma unroll
                for (int ni = 0; ni < 4; ++ni)
                    c[mi][ni] = f32x4{0.f, 0.f, 0.f, 0.f};

            // A from LDS (f32 -> hi/lo bf16), B frags from blob (L=1+l)
            const int lbase = (1 + l) * 16;
            #pragma unroll
            for (int kc = 0; kc < 2; ++kc) {
                bf16x8 ahi[2], alo[2];
                #pragma unroll
                for (int mi = 0; mi < 2; ++mi) {
                    const float* rp = Hw + rbase + mi * 1088 + kc * 32;
                    const f32x4 f0 = *(const f32x4*)(rp);
                    const f32x4 f1 = *(const f32x4*)(rp + 4);
                    float fe[8] = {f0[0], f0[1], f0[2], f0[3], f1[0], f1[1], f1[2], f1[3]};
                    unsigned hw[4], lw[4];
                    #pragma unroll
                    for (int w = 0; w < 4; ++w) {
                        const unsigned h0 = bf16rne(fe[2*w]), h1 = bf16rne(fe[2*w+1]);
                        hw[w] = h0 | (h1 << 16);
                        const float l0 = fe[2*w] - bf16tof(h0), l1 = fe[2*w+1] - bf16tof(h1);
                        lw[w] = bf16rne(l0) | (bf16rne(l1) << 16);
                    }
                    ahi[mi] = tofrag(hw[0], hw[1], hw[2], hw[3]);
                    alo[mi] = tofrag(lw[0], lw[1], lw[2], lw[3]);
                }
                #pragma unroll
                for (int ni = 0; ni < 4; ++ni) {
                    const bf16x8 bhi = tofrag4(fragp[(lbase + (kc * 4 + ni) * 2 + 0) * 64 + lane]);
                    const bf16x8 blo = tofrag4(fragp[(lbase + (kc * 4 + ni) * 2 + 1) * 64 + lane]);
                    #pragma unroll
                    for (int mi = 0; mi < 2; ++mi) {
                        c[mi][ni] = __builtin_amdgcn_mfma_f32_16x16x32_bf16(ahi[mi], bhi, c[mi][ni], 0, 0, 0);
                        c[mi][ni] = __builtin_amdgcn_mfma_f32_16x16x32_bf16(ahi[mi], blo, c[mi][ni], 0, 0, 0);
                        c[mi][ni] = __builtin_amdgcn_mfma_f32_16x16x32_bf16(alo[mi], bhi, c[mi][ni], 0, 0, 0);
                    }
                }
            }
            #pragma unroll
            for (int ni = 0; ni < 4; ++ni) {
                const float bm = b_mid[l * DH + ni * 16 + l15];
                #pragma unroll
                for (int mi = 0; mi < 2; ++mi) {
                    c[mi][ni][0] += bm; c[mi][ni][1] += bm;
                    c[mi][ni][2] += bm; c[mi][ni][3] += bm;
                }
            }
        }

        // ---- heads: final relu, dot over d (ni-regs + 16-lane reduce)
        #pragma unroll
        for (int mi = 0; mi < 2; ++mi)
            #pragma unroll
            for (int ni = 0; ni < 4; ++ni)
                #pragma unroll
                for (int rr = 0; rr < 4; ++rr)
                    c[mi][ni][rr] = fmaxf(c[mi][ni][rr], 0.0f);

        float ca[2][4], da[2][4];
        #pragma unroll
        for (int mi = 0; mi < 2; ++mi)
            #pragma unroll
            for (int rr = 0; rr < 4; ++rr) {
                float sc = 0.f, sd = 0.f;
                #pragma unroll
                for (int ni = 0; ni < 4; ++ni) {
                    sc = fmaf(c[mi][ni][rr], wc[ni], sc);
                    sd = fmaf(c[mi][ni][rr], wd[ni], sd);
                }
                sc += __shfl_xor(sc, 1); sc += __shfl_xor(sc, 2);
                sc += __shfl_xor(sc, 4); sc += __shfl_xor(sc, 8);
                sd += __shfl_xor(sd, 1); sd += __shfl_xor(sd, 2);
                sd += __shfl_xor(sd, 4); sd += __shfl_xor(sd, 8);
                ca[mi][rr] = sc; da[mi][rr] = sd;
            }

        // lanes with l15 < 8 finalize: combo cc = l15&7 -> item mi*16 + g*4 + rr
        float selc = ca[0][0], seld = da[0][0], seli = invp[0][0];
        #pragma unroll
        for (int cc = 1; cc < 8; ++cc) {
            const bool m = ((l15 & 7) == cc);
            selc = m ? ca[cc >> 2][cc & 3]   : selc;
            seld = m ? da[cc >> 2][cc & 3]   : seld;
            seli = m ? invp[cc >> 2][cc & 3] : seli;
        }
        if (l15 < 8) {
            const int item_local = ((l15 >> 2) << 4) + (g << 2) + (l15 & 3);
            unsigned idx = base + (unsigned)item_local;
            if (idx >= T) idx = T - 1;
            const unsigned pk = work[idx];
            const unsigned rr_ = pk & 0xFFFFFu;
            const float tt1 = t1[pk];
            const float dt  = t2[pk] - tt1;

            float clsv = selc + bcls;
            float dval = fmaf(seld + bdst, dt, tt1);

            const float thr = fminf(fmaxf(1e-5f * seli, 3e-4f), 2e-2f);
            if ((fabsf(clsv) < thr) || (fabsf(dval) < thr)) {
                slow_eval(orig, vec, t1, t2, (size_t)pk, rr_,
                          W_in, b_in, ln_g, ln_b, W_mid, b_mid,
                          W_cls, b_cls, W_dist, b_dist, clsv, dval);
            }
            if (clsv > 0.0f)
                atomicMin(arena + rr_, fkey(dval));
        }
    }
}

// ---------------------------------------------------------------------------
// FALLBACK (round-5 style, known-good, self-contained) for unexpected R/ws.
// ---------------------------------------------------------------------------
__global__ __launch_bounds__(256, 2)
void fallback_k(const float* __restrict__ orig, const float* __restrict__ vec,
                const float* __restrict__ t1,   const float* __restrict__ t2,
                const int*   __restrict__ mask,
                const float* __restrict__ W_in,  const float* __restrict__ b_in,
                const float* __restrict__ ln_g,  const float* __restrict__ ln_b,
                const float* __restrict__ W_mid, const float* __restrict__ b_mid,
                const float* __restrict__ W_cls, const float* __restrict__ b_cls,
                const float* __restrict__ W_dist,const float* __restrict__ b_dist,
                float* __restrict__ out, int R)
{
    __shared__ __align__(16) float wlds[DIN*DH + NLAYER*DH*DH];
    __shared__ __align__(16) float act[4][32][64];

    const int tid  = threadIdx.x;
    const int lane = tid & 63;
    const int wv   = tid >> 6;

    {
        f32x4*       dst = (f32x4*)wlds;
        const f32x4* s1  = (const f32x4*)W_in;
        const f32x4* s2  = (const f32x4*)W_mid;
        #pragma unroll 1
        for (int idx = tid; idx < DIN*DH/4; idx += 256)        dst[idx] = s1[idx];
        #pragma unroll 1
        for (int idx = tid; idx < NLAYER*DH*DH/4; idx += 256)  dst[DIN*DH/4 + idx] = s2[idx];
    }
    __syncthreads();

    const float* win_l  = wlds;
    const float* wmid_l = wlds + DIN*DH;

    const int r = blockIdx.x * 256 + tid;
    if (r >= R) return;

    float* myact = &act[wv][0][lane];

    const float o0 = orig[3*r+0], o1 = orig[3*r+1], o2 = orig[3*r+2];
    const float v0 = vec[3*r+0],  v1 = vec[3*r+1],  v2 = vec[3*r+2];

    float dist = BIGV;

    #pragma unroll 1
    for (int i = 0; i < NITER; ++i) {
        const float t1i = t1[(size_t)i * R + r];
        const float t2i = t2[(size_t)i * R + r];
        const int   mi  = mask[(size_t)i * R + r];
        if (!mi) continue;
        const float dt = t2i - t1i;

        const float io0 = fmaf(v0, t1i, o0);
        const float io1 = fmaf(v1, t1i, o1);
        const float io2 = fmaf(v2, t1i, o2);
        const float iv0 = v0 * dt, iv1 = v1 * dt, iv2 = v2 * dt;

        float a[DH];
        #pragma unroll
        for (int d = 0; d < DH; ++d) a[d] = 0.0f;

        #pragma unroll 1
        for (int p = 0; p < P; ++p) {
            const float tp = (float)p * (1.0f / 15.0f);
            const float x0 = fmaf(iv0, tp, io0) * INV_R;
            const float x1 = fmaf(iv1, tp, io1) * INV_R;
            const float x2 = fmaf(iv2, tp, io2) * INV_R;
            const f32x4* w0 = (const f32x4*)(win_l + (3*p+0)*DH);
            const f32x4* w1 = (const f32x4*)(win_l + (3*p+1)*DH);
            const f32x4* w2 = (const f32x4*)(win_l + (3*p+2)*DH);
            #pragma unroll
            for (int j = 0; j < 16; ++j) {
                const f32x4 u = w0[j], v4 = w1[j], w4 = w2[j];
                a[4*j+0] = fmaf(x2, w4.x, fmaf(x1, v4.x, fmaf(x0, u.x, a[4*j+0])));
                a[4*j+1] = fmaf(x2, w4.y, fmaf(x1, v4.y, fmaf(x0, u.y, a[4*j+1])));
                a[4*j+2] = fmaf(x2, w4.z, fmaf(x1, v4.z, fmaf(x0, u.z, a[4*j+2])));
                a[4*j+3] = fmaf(x2, w4.w, fmaf(x1, v4.w, fmaf(x0, u.w, a[4*j+3])));
            }
        }
        #pragma unroll
        for (int d = 0; d < DH; ++d) a[d] += b_in[d];

        float invprod = 1.0f;

        #pragma unroll 1
        for (int l = 0; l < NLAYER; ++l) {
            #pragma unroll
            for (int d = 0; d < DH; ++d) a[d] = fmaxf(a[d], 0.0f);

            float mu = 0.0f;
            #pragma unroll
            for (int d = 0; d < DH; ++d) mu += a[d];
            mu *= (1.0f / 64.0f);

            float var = 0.0f;
            #pragma unroll
            for (int d = 0; d < DH; ++d) {
                const float cdev = a[d] - mu;
                var = fmaf(cdev, cdev, var);
            }
            var *= (1.0f / 64.0f);
            const float inv = 1.0f / sqrtf(var + 1e-5f);
            invprod *= inv;

            const float* gp = ln_g + l*DH;
            const float* bp = ln_b + l*DH;

            #pragma unroll
            for (int d = 0; d < 32; ++d)
                myact[d*64] = fmaf((a[d] - mu) * inv, gp[d], bp[d]);
            float hh[32];
            #pragma unroll
            for (int j = 0; j < 32; ++j)
                hh[j] = fmaf((a[32+j] - mu) * inv, gp[32+j], bp[32+j]);

            #pragma unroll
            for (int d = 0; d < DH; ++d) a[d] = 0.0f;

            const float* Wl = wmid_l + l*DH*DH;
            #pragma unroll 4
            for (int k = 0; k < 32; ++k) {
                const float hk = myact[k*64];
                const f32x4* wr = (const f32x4*)(Wl + k*DH);
                #pragma unroll
                for (int j = 0; j < 16; ++j) {
                    const f32x4 w4 = wr[j];
                    a[4*j+0] = fmaf(hk, w4.x, a[4*j+0]);
                    a[4*j+1] = fmaf(hk, w4.y, a[4*j+1]);
                    a[4*j+2] = fmaf(hk, w4.z, a[4*j+2]);
                    a[4*j+3] = fmaf(hk, w4.w, a[4*j+3]);
                }
            }
            #pragma unroll
            for (int j = 0; j < 32; ++j)
                myact[j*64] = hh[j];
            #pragma unroll 4
            for (int k = 32; k < DH; ++k) {
                const float hk = myact[(k-32)*64];
                const f32x4* wr = (const f32x4*)(Wl + k*DH);
                #pragma unroll
                for (int j = 0; j < 16; ++j) {
                    const f32x4 w4 = wr[j];
                    a[4*j+0] = fmaf(hk, w4.x, a[4*j+0]);
                    a[4*j+1] = fmaf(hk, w4.y, a[4*j+1]);
                    a[4*j+2] = fmaf(hk, w4.z, a[4*j+2]);
                    a[4*j+3] = fmaf(hk, w4.w, a[4*j+3]);
                }
            }
            const float* bm = b_mid + l*DH;
            #pragma unroll
            for (int d = 0; d < DH; ++d) a[d] += bm[d];
        }

        #pragma unroll
        for (int d = 0; d < DH; ++d) a[d] = fmaxf(a[d], 0.0f);

        float c0 = 0.f, c1 = 0.f, c2 = 0.f, c3 = 0.f;
        float e0 = 0.f, e1 = 0.f, e2 = 0.f, e3 = 0.f;
        #pragma unroll
        for (int j = 0; j < 16; ++j) {
            c0 = fmaf(a[4*j+0], W_cls[4*j+0],  c0);
            c1 = fmaf(a[4*j+1], W_cls[4*j+1],  c1);
            c2 = fmaf(a[4*j+2], W_cls[4*j+2],  c2);
            c3 = fmaf(a[4*j+3], W_cls[4*j+3],  c3);
            e0 = fmaf(a[4*j+0], W_dist[4*j+0], e0);
            e1 = fmaf(a[4*j+1], W_dist[4*j+1], e1);
            e2 = fmaf(a[4*j+2], W_dist[4*j+2], e2);
            e3 = fmaf(a[4*j+3], W_dist[4*j+3], e3);
        }
        float cls = ((c0 + c1) + (c2 + c3)) + b_cls[0];
        float dv  = ((e0 + e1) + (e2 + e3)) + b_dist[0];
        float dval = fmaf(dv, dt, t1i);

        float thr = 2e-6f * invprod;
        thr = fminf(fmaxf(thr, 3e-5f), 2e-2f);
        if ((fabsf(cls) < thr) || (fabsf(dval) < thr)) {
            slow_eval(orig, vec, t1, t2, (size_t)i * R + r, (unsigned)r,
                      W_in, b_in, ln_g, ln_b, W_mid, b_mid,
                      W_cls, b_cls, W_dist, b_dist, cls, dval);
        }

        if (cls > 0.0f && dval < dist) dist = dval;
    }

    const float dfin = (dist == BIGV) ? 0.0f : dist;
    out[r]     = (dfin > 0.0f) ? 1.0f : 0.0f;
    out[R + r] = dfin;
}

extern "C" void kernel_launch(void* const* d_in, const int* in_sizes, int n_in,
                              void* d_out, int out_size, void* d_ws, size_t ws_size,
                              hipStream_t stream) {
    const float* orig   = (const float*)d_in[0];
    const float* vec    = (const float*)d_in[1];
    const float* t1     = (const float*)d_in[2];
    const float* t2     = (const float*)d_in[3];
    const int*   mask   = (const int*)  d_in[4];
    const float* W_in   = (const float*)d_in[5];
    const float* b_in   = (const float*)d_in[6];
    const float* ln_g   = (const float*)d_in[7];
    const float* ln_b   = (const float*)d_in[8];
    const float* W_mid  = (const float*)d_in[9];
    const float* b_mid  = (const float*)d_in[10];
    const float* W_cls  = (const float*)d_in[11];
    const float* b_cls  = (const float*)d_in[12];
    const float* W_dist = (const float*)d_in[13];
    const float* b_dist = (const float*)d_in[14];

    float* out = (float*)d_out;
    const int R = in_sizes[0] / 3;

    const size_t need_ws = 16 + 4ull * (size_t)R * NITER;
    const bool fast = (R == (1 << RLOG)) && (ws_size >= need_ws);

    if (fast) {
        unsigned* cnt   = (unsigned*)d_ws;
        unsigned* work  = (unsigned*)d_ws + 4;   // 16B offset
        unsigned* arena = (unsigned*)d_out + R;  // out[R..2R) as key arena

        hipMemsetAsync(cnt, 0, 4, stream);
        compact_k<<<(R * NITER) / 256, 256, 0, stream>>>(mask, cnt, work);
        prep_k<<<48, 256, 0, stream>>>(W_in, W_mid);
        init_k<<<1024, 256, 0, stream>>>(arena, R);
        mfma_k<<<2048, 256, 0, stream>>>(orig, vec, t1, t2,
                                         W_in, b_in, ln_g, ln_b, W_mid, b_mid,
                                         W_cls, b_cls, W_dist, b_dist,
                                         work, cnt, arena);
        finalize_k<<<1024, 256, 0, stream>>>(out, R);
    } else {
        const int threads = 256;
        const int blocks  = (R + threads - 1) / threads;
        fallback_k<<<blocks, threads, 0, stream>>>(
            orig, vec, t1, t2, mask,
            W_in, b_in, ln_g, ln_b, W_mid, b_mid,
            W_cls, b_cls, W_dist, b_dist,
            out, R);
    }
}

// Round 13
// 6805.491 us; speedup vs baseline: 1.4377x; 1.4377x over previous
//
#include <hip/hip_runtime.h>
#include <math.h>

constexpr int   P      = 16;   // N_POINTS
constexpr int   DIN    = 48;   // P*3
constexpr int   DH     = 64;   // hidden dim
constexpr int   NITER  = 8;    // I
constexpr int   NLAYER = 2;    // L
constexpr float BIGV   = 1e9f;
constexpr float INV_R  = 1.0f / 2.5f;
constexpr int   RLOG   = 20;   // fast path requires R == 1<<20

typedef float f32x4 __attribute__((ext_vector_type(4)));
typedef const __attribute__((address_space(1))) f32x4 gf4_t;

// Launder a wave-uniform address onto the VMEM/vmcnt path (validated R4/R7/R8).
__device__ __forceinline__ gf4_t* vmem(const float* p) {
    unsigned long long a = (unsigned long long)p;
    asm volatile("" : "+v"(a));
    return (gf4_t*)a;
}

// monotonic float<->uint key map (total order)
__device__ __forceinline__ unsigned fkey(float f) {
    unsigned b = __float_as_uint(f);
    return (b & 0x80000000u) ? ~b : (b | 0x80000000u);
}
__device__ __forceinline__ float funkey(unsigned k) {
    unsigned b = (k & 0x80000000u) ? (k ^ 0x80000000u) : ~k;
    return __uint_as_float(b);
}

// ---------------------------------------------------------------------------
// SLOW PATH (rare): correctly-rounded f32 elementwise, f64 reductions.
// Verbatim from all passing rounds.
// ---------------------------------------------------------------------------
__device__ __noinline__
void slow_eval(const float* __restrict__ orig, const float* __restrict__ vec,
               const float* __restrict__ t1,   const float* __restrict__ t2,
               size_t tidx, unsigned r,
               const float* __restrict__ W_in,  const float* __restrict__ b_in,
               const float* __restrict__ ln_g,  const float* __restrict__ ln_b,
               const float* __restrict__ W_mid, const float* __restrict__ b_mid,
               const float* __restrict__ W_cls, const float* __restrict__ b_cls,
               const float* __restrict__ W_dist,const float* __restrict__ b_dist,
               float& cls_o, float& dval_o)
{
    const float o0 = orig[3*r+0], o1 = orig[3*r+1], o2 = orig[3*r+2];
    const float v0 = vec[3*r+0],  v1 = vec[3*r+1],  v2 = vec[3*r+2];
    const float t1i = t1[tidx], t2i = t2[tidx];

    const float dt  = __fsub_rn(t2i, t1i);
    const float io0 = __fadd_rn(o0, __fmul_rn(v0, t1i));
    const float io1 = __fadd_rn(o1, __fmul_rn(v1, t1i));
    const float io2 = __fadd_rn(o2, __fmul_rn(v2, t1i));
    const float iv0 = __fmul_rn(v0, dt);
    const float iv1 = __fmul_rn(v1, dt);
    const float iv2 = __fmul_rn(v2, dt);
    const float delta = 1.0f / 15.0f;

    float x[DIN];
    #pragma unroll
    for (int p = 0; p < P; ++p) {
        const float tp = __fmul_rn((float)p, delta);
        x[3*p+0] = __fdiv_rn(__fadd_rn(io0, __fmul_rn(iv0, tp)), 2.5f);
        x[3*p+1] = __fdiv_rn(__fadd_rn(io1, __fmul_rn(iv1, tp)), 2.5f);
        x[3*p+2] = __fdiv_rn(__fadd_rn(io2, __fmul_rn(iv2, tp)), 2.5f);
    }

    float a[DH];
    #pragma unroll 1
    for (int d = 0; d < DH; ++d) {
        double acc0 = 0.0, acc1 = 0.0;
        #pragma unroll
        for (int k = 0; k < DIN; k += 2) {
            acc0 = fma((double)x[k],   (double)W_in[k*DH + d],     acc0);
            acc1 = fma((double)x[k+1], (double)W_in[(k+1)*DH + d], acc1);
        }
        a[d] = __fadd_rn((float)(acc0 + acc1), b_in[d]);
    }

    #pragma unroll 1
    for (int l = 0; l < NLAYER; ++l) {
        #pragma unroll 1
        for (int d = 0; d < DH; ++d) a[d] = fmaxf(a[d], 0.0f);

        double s = 0.0;
        #pragma unroll 1
        for (int d = 0; d < DH; ++d) s += (double)a[d];
        const float mu = (float)(s * (1.0 / 64.0));

        double vs = 0.0;
        #pragma unroll 1
        for (int d = 0; d < DH; ++d) {
            const float c = __fsub_rn(a[d], mu);
            vs = fma((double)c, (double)c, vs);
        }
        const float var = (float)(vs * (1.0 / 64.0));
        const float ve  = __fadd_rn(var, 1e-5f);
        const float inv = (float)(1.0 / sqrt((double)ve));

        float hn[DH];
        #pragma unroll 1
        for (int d = 0; d < DH; ++d) {
            float t = __fsub_rn(a[d], mu);
            t = __fmul_rn(t, inv);
            t = __fmul_rn(t, ln_g[l*DH + d]);
            hn[d] = __fadd_rn(t, ln_b[l*DH + d]);
        }

        #pragma unroll 1
        for (int d = 0; d < DH; ++d) {
            double acc0 = 0.0, acc1 = 0.0;
            #pragma unroll
            for (int k = 0; k < DH; k += 2) {
                acc0 = fma((double)hn[k],   (double)W_mid[(l*DH + k)*DH + d],   acc0);
                acc1 = fma((double)hn[k+1], (double)W_mid[(l*DH + k+1)*DH + d], acc1);
            }
            a[d] = __fadd_rn((float)(acc0 + acc1), b_mid[l*DH + d]);
        }
    }

    double c0 = 0.0, c1 = 0.0, d0 = 0.0, d1 = 0.0;
    #pragma unroll 1
    for (int d = 0; d < DH; d += 2) {
        const float h0 = fmaxf(a[d],   0.0f);
        const float h1 = fmaxf(a[d+1], 0.0f);
        c0 = fma((double)h0, (double)W_cls[d],    c0);
        c1 = fma((double)h1, (double)W_cls[d+1],  c1);
        d0 = fma((double)h0, (double)W_dist[d],   d0);
        d1 = fma((double)h1, (double)W_dist[d+1], d1);
    }
    const float cls = __fadd_rn((float)(c0 + c1), b_cls[0]);
    const float dv  = __fadd_rn((float)(d0 + d1), b_dist[0]);
    cls_o  = cls;
    dval_o = __fadd_rn(__fmul_rn(dv, dt), t1i);
}

// ---------------------------------------------------------------------------
// Compaction / init / finalize (verbatim from passing rounds)
// ---------------------------------------------------------------------------
__global__ __launch_bounds__(256)
void compact_k(const int* __restrict__ mask, unsigned* __restrict__ cnt,
               unsigned* __restrict__ work)
{
    const int idx  = blockIdx.x * 256 + threadIdx.x;
    const int lane = threadIdx.x & 63;
    const bool m = (mask[idx] != 0);
    const unsigned long long b = __ballot(m);
    const int nact = __popcll(b);
    unsigned base = 0;
    if (lane == 0 && nact) base = atomicAdd(cnt, (unsigned)nact);
    base = __shfl(base, 0);
    if (m) {
        const int pre = __popcll(b & ((1ull << lane) - 1ull));
        work[base + pre] = (unsigned)idx;
    }
}

__global__ __launch_bounds__(256)
void init_k(unsigned* __restrict__ arena, int R)
{
    const unsigned key_big = fkey(BIGV);
    for (int r = blockIdx.x * 256 + threadIdx.x; r < R; r += gridDim.x * 256)
        arena[r] = key_big;
}

__global__ __launch_bounds__(256)
void finalize_k(float* __restrict__ out, int R)
{
    unsigned* arena = (unsigned*)out + R;
    for (int r = blockIdx.x * 256 + threadIdx.x; r < R; r += gridDim.x * 256) {
        const float dist = funkey(arena[r]);
        const float dfin = (dist == BIGV) ? 0.0f : dist;
        out[r] = (dfin > 0.0f) ? 1.0f : 0.0f;
        ((float*)arena)[r] = dfin;
    }
}

// ---------------------------------------------------------------------------
// k-half matmul for the mid layers: 32 sequential k-steps, weights from LDS
// (layer 0) or laundered global / L2 (layer 1). Inner fmaf order identical
// to R6/R7/R8 (validated): per component, acc0 then acc1.
// ---------------------------------------------------------------------------
template<bool GLOBAL>
__device__ __forceinline__
void mm_khalf(const float* Wbase, int kofs,
              const float* col0, const float* col1,
              float (&a0)[DH], float (&a1)[DH])
{
    #pragma unroll 2
    for (int k = 0; k < 32; ++k) {
        const float hk0 = col0[k*128];
        const float hk1 = col1[k*128];
        if constexpr (GLOBAL) {
            gf4_t* wr = vmem(Wbase + (kofs + k)*DH);
            #pragma unroll
            for (int j = 0; j < 16; ++j) {
                const f32x4 w4 = wr[j];
                a0[4*j+0] = fmaf(hk0, w4.x, a0[4*j+0]);
                a1[4*j+0] = fmaf(hk1, w4.x, a1[4*j+0]);
                a0[4*j+1] = fmaf(hk0, w4.y, a0[4*j+1]);
                a1[4*j+1] = fmaf(hk1, w4.y, a1[4*j+1]);
                a0[4*j+2] = fmaf(hk0, w4.z, a0[4*j+2]);
                a1[4*j+2] = fmaf(hk1, w4.z, a1[4*j+2]);
                a0[4*j+3] = fmaf(hk0, w4.w, a0[4*j+3]);
                a1[4*j+3] = fmaf(hk1, w4.w, a1[4*j+3]);
            }
        } else {
            const f32x4* wr = (const f32x4*)(Wbase + (kofs + k)*DH);
            #pragma unroll
            for (int j = 0; j < 16; ++j) {
                const f32x4 w4 = wr[j];
                a0[4*j+0] = fmaf(hk0, w4.x, a0[4*j+0]);
                a1[4*j+0] = fmaf(hk1, w4.x, a1[4*j+0]);
                a0[4*j+1] = fmaf(hk0, w4.y, a0[4*j+1]);
                a1[4*j+1] = fmaf(hk1, w4.y, a1[4*j+1]);
                a0[4*j+2] = fmaf(hk0, w4.z, a0[4*j+2]);
                a1[4*j+2] = fmaf(hk1, w4.z, a1[4*j+2]);
                a0[4*j+3] = fmaf(hk0, w4.w, a0[4*j+3]);
                a1[4*j+3] = fmaf(hk1, w4.w, a1[4*j+3]);
            }
        }
    }
}

// ---------------------------------------------------------------------------
// MAIN: 256 threads (4 waves), 2 items/lane, __launch_bounds__(256,1) ->
// ~192 VGPR (R6/R12 evidence) -> acc[2][64] stays in registers, no spill.
// LDS = act[4][32][128] (64 KB) + W_mid layer-0 (16 KB) = 80 KB exactly ->
// 2 blocks/CU = 8 waves/CU (first time both no-spill AND 8 waves).
// Layer-1 weights ride the vmcnt pipe (L2-resident 16 KB) -> waves in
// layer-0 (LDS pipe) and layer-1 (VMEM pipe) overlap across the CU.
// Per-item FP sequence identical to R6/R7/R8 (absmax 0.0039).
// ---------------------------------------------------------------------------
__global__ __launch_bounds__(256, 1)
void main2_k(const float* __restrict__ orig,
             const float* __restrict__ vec,
             const float* __restrict__ t1,
             const float* __restrict__ t2,
             const float* __restrict__ W_in,
             const float* __restrict__ b_in,
             const float* __restrict__ ln_g,
             const float* __restrict__ ln_b,
             const float* __restrict__ W_mid,
             const float* __restrict__ b_mid,
             const float* __restrict__ W_cls,
             const float* __restrict__ b_cls,
             const float* __restrict__ W_dist,
             const float* __restrict__ b_dist,
             const unsigned* __restrict__ work,
             const unsigned* __restrict__ cnt,
             unsigned* __restrict__ arena)
{
    __shared__ __align__(16) float wl0[DH*DH];       // 16 KiB: W_mid layer 0
    __shared__ __align__(16) float act[4][32][128];  // 64 KiB

    const int tid  = threadIdx.x;
    const int lane = tid & 63;
    const int wv   = tid >> 6;

    {   // stage W_mid layer 0 (whole block), one barrier
        f32x4*       dst = (f32x4*)wl0;
        const f32x4* s2  = (const f32x4*)W_mid;
        #pragma unroll 1
        for (int idx = tid; idx < DH*DH/4; idx += 256) dst[idx] = s2[idx];
    }
    __syncthreads();

    float* col0 = &act[wv][0][lane];        // item A column, stride 128 floats
    float* col1 = &act[wv][0][64 + lane];   // item B column

    const unsigned T    = *cnt;
    const unsigned gtid = blockIdx.x * 256 + tid;
    const unsigned NTOT = gridDim.x * 256;

    for (unsigned g = gtid; 2*g < T; g += NTOT) {
        const unsigned jA = 2*g, jB = 2*g + 1;
        unsigned pk2[2];
        pk2[0] = work[jA];
        pk2[1] = (jB < T) ? work[jB] : pk2[0];   // duplicate-safe tail

        float t1v[2], dtv[2], iov[2][3], ivv[2][3];
        #pragma unroll
        for (int it = 0; it < 2; ++it) {
            const unsigned pkk = pk2[it];
            const unsigned r   = pkk & 0xFFFFFu;
            const float tt1 = t1[pkk], tt2 = t2[pkk];
            t1v[it] = tt1; dtv[it] = tt2 - tt1;
            const float o0 = orig[3*r+0], o1 = orig[3*r+1], o2 = orig[3*r+2];
            const float v0 = vec[3*r+0],  v1 = vec[3*r+1],  v2 = vec[3*r+2];
            iov[it][0] = fmaf(v0, tt1, o0);
            iov[it][1] = fmaf(v1, tt1, o1);
            iov[it][2] = fmaf(v2, tt1, o2);
            ivv[it][0] = v0 * dtv[it];
            ivv[it][1] = v1 * dtv[it];
            ivv[it][2] = v2 * dtv[it];
        }

        float acc[2][DH];
        #pragma unroll
        for (int it = 0; it < 2; ++it)
            #pragma unroll
            for (int d = 0; d < DH; ++d) acc[it][d] = 0.0f;

        // ---- input layer: x inline; W_in rows from global (L1, vmcnt pipe)
        #pragma unroll 1
        for (int p = 0; p < P; ++p) {
            const float tp = (float)p * (1.0f / 15.0f);
            float xx[2][3];
            #pragma unroll
            for (int it = 0; it < 2; ++it) {
                xx[it][0] = fmaf(ivv[it][0], tp, iov[it][0]) * INV_R;
                xx[it][1] = fmaf(ivv[it][1], tp, iov[it][1]) * INV_R;
                xx[it][2] = fmaf(ivv[it][2], tp, iov[it][2]) * INV_R;
            }
            gf4_t* w0 = vmem(W_in + (3*p+0)*DH);
            gf4_t* w1 = vmem(W_in + (3*p+1)*DH);
            gf4_t* w2 = vmem(W_in + (3*p+2)*DH);
            #pragma unroll
            for (int j = 0; j < 16; ++j) {
                const f32x4 u = w0[j], v4 = w1[j], w4 = w2[j];
                #pragma unroll
                for (int it = 0; it < 2; ++it) {
                    acc[it][4*j+0] = fmaf(xx[it][2], w4.x, fmaf(xx[it][1], v4.x, fmaf(xx[it][0], u.x, acc[it][4*j+0])));
                    acc[it][4*j+1] = fmaf(xx[it][2], w4.y, fmaf(xx[it][1], v4.y, fmaf(xx[it][0], u.y, acc[it][4*j+1])));
                    acc[it][4*j+2] = fmaf(xx[it][2], w4.z, fmaf(xx[it][1], v4.z, fmaf(xx[it][0], u.z, acc[it][4*j+2])));
                    acc[it][4*j+3] = fmaf(xx[it][2], w4.w, fmaf(xx[it][1], v4.w, fmaf(xx[it][0], u.w, acc[it][4*j+3])));
                }
            }
        }
        #pragma unroll
        for (int it = 0; it < 2; ++it)
            #pragma unroll
            for (int d = 0; d < DH; ++d) acc[it][d] += b_in[d];

        float invprod[2] = {1.0f, 1.0f};

        // ---- mid layers: relu -> LN -> k-halved matmul
        // layer 0 weights: LDS (wl0). layer 1 weights: laundered global (L2).
        #pragma unroll
        for (int l = 0; l < NLAYER; ++l) {
            float hh[2][32];
            #pragma unroll
            for (int it = 0; it < 2; ++it) {
                #pragma unroll
                for (int d = 0; d < DH; ++d) acc[it][d] = fmaxf(acc[it][d], 0.0f);

                float mu = 0.0f;
                #pragma unroll
                for (int d = 0; d < DH; ++d) mu += acc[it][d];
                mu *= (1.0f / 64.0f);

                float var = 0.0f;
                #pragma unroll
                for (int d = 0; d < DH; ++d) {
                    const float c = acc[it][d] - mu;
                    var = fmaf(c, c, var);
                }
                var *= (1.0f / 64.0f);
                const float inv = 1.0f / sqrtf(var + 1e-5f);
                invprod[it] *= inv;

                const float* gg = ln_g + l*DH;
                const float* bb = ln_b + l*DH;
                float* col = it ? col1 : col0;
                #pragma unroll
                for (int d = 0; d < 32; ++d)
                    col[d*128] = fmaf((acc[it][d] - mu) * inv, gg[d], bb[d]);
                #pragma unroll
                for (int j = 0; j < 32; ++j)
                    hh[it][j] = fmaf((acc[it][32+j] - mu) * inv, gg[32+j], bb[32+j]);
            }

            #pragma unroll
            for (int it = 0; it < 2; ++it)
                #pragma unroll
                for (int d = 0; d < DH; ++d) acc[it][d] = 0.0f;

            // k = 0..31 (lower halves in LDS columns)
            if (l == 0) mm_khalf<false>(wl0,             0, col0, col1, acc[0], acc[1]);
            else        mm_khalf<true >(W_mid + DH*DH,   0, col0, col1, acc[0], acc[1]);

            #pragma unroll
            for (int j = 0; j < 32; ++j) {   // park upper halves (in-order DS)
                col0[j*128] = hh[0][j];
                col1[j*128] = hh[1][j];
            }

            // k = 32..63
            if (l == 0) mm_khalf<false>(wl0,            32, col0, col1, acc[0], acc[1]);
            else        mm_khalf<true >(W_mid + DH*DH,  32, col0, col1, acc[0], acc[1]);

            const float* bm = b_mid + l*DH;
            #pragma unroll
            for (int it = 0; it < 2; ++it)
                #pragma unroll
                for (int d = 0; d < DH; ++d) acc[it][d] += bm[d];
        }

        // ---- heads + borderline recheck + atomic min (per item)
        #pragma unroll
        for (int it = 0; it < 2; ++it) {
            #pragma unroll
            for (int d = 0; d < DH; ++d) acc[it][d] = fmaxf(acc[it][d], 0.0f);

            float c0 = 0.f, c1 = 0.f, c2 = 0.f, c3 = 0.f;
            float e0 = 0.f, e1 = 0.f, e2 = 0.f, e3 = 0.f;
            #pragma unroll
            for (int j = 0; j < 16; ++j) {
                c0 = fmaf(acc[it][4*j+0], W_cls[4*j+0],  c0);
                c1 = fmaf(acc[it][4*j+1], W_cls[4*j+1],  c1);
                c2 = fmaf(acc[it][4*j+2], W_cls[4*j+2],  c2);
                c3 = fmaf(acc[it][4*j+3], W_cls[4*j+3],  c3);
                e0 = fmaf(acc[it][4*j+0], W_dist[4*j+0], e0);
                e1 = fmaf(acc[it][4*j+1], W_dist[4*j+1], e1);
                e2 = fmaf(acc[it][4*j+2], W_dist[4*j+2], e2);
                e3 = fmaf(acc[it][4*j+3], W_dist[4*j+3], e3);
            }
            float cls = ((c0 + c1) + (c2 + c3)) + b_cls[0];
            float dv  = ((e0 + e1) + (e2 + e3)) + b_dist[0];
            float dval = fmaf(dv, dtv[it], t1v[it]);

            float thr = 2e-6f * invprod[it];
            thr = fminf(fmaxf(thr, 3e-5f), 2e-2f);
            const unsigned r = pk2[it] & 0xFFFFFu;
            if ((fabsf(cls) < thr) || (fabsf(dval) < thr)) {
                slow_eval(orig, vec, t1, t2, (size_t)pk2[it], r,
                          W_in, b_in, ln_g, ln_b, W_mid, b_mid,
                          W_cls, b_cls, W_dist, b_dist, cls, dval);
            }
            if (cls > 0.0f)
                atomicMin(arena + r, fkey(dval));
        }
    }
}

// ---------------------------------------------------------------------------
// FALLBACK (round-5 kernel, known-good) for unexpected R / small workspace.
// ---------------------------------------------------------------------------
__global__ __launch_bounds__(256, 2)
void fallback_k(const float* __restrict__ orig, const float* __restrict__ vec,
                const float* __restrict__ t1,   const float* __restrict__ t2,
                const int*   __restrict__ mask,
                const float* __restrict__ W_in,  const float* __restrict__ b_in,
                const float* __restrict__ ln_g,  const float* __restrict__ ln_b,
                const float* __restrict__ W_mid, const float* __restrict__ b_mid,
                const float* __restrict__ W_cls, const float* __restrict__ b_cls,
                const float* __restrict__ W_dist,const float* __restrict__ b_dist,
                float* __restrict__ out, int R)
{
    __shared__ __align__(16) float wlds[DIN*DH + NLAYER*DH*DH];
    __shared__ __align__(16) float act[4][32][64];

    const int tid  = threadIdx.x;
    const int lane = tid & 63;
    const int wv   = tid >> 6;

    {
        f32x4*       dst = (f32x4*)wlds;
        const f32x4* s1  = (const f32x4*)W_in;
        const f32x4* s2  = (const f32x4*)W_mid;
        #pragma unroll 1
        for (int idx = tid; idx < DIN*DH/4; idx += 256)        dst[idx] = s1[idx];
        #pragma unroll 1
        for (int idx = tid; idx < NLAYER*DH*DH/4; idx += 256)  dst[DIN*DH/4 + idx] = s2[idx];
    }
    __syncthreads();

    const float* win_l  = wlds;
    const float* wmid_l = wlds + DIN*DH;

    const int r = blockIdx.x * 256 + tid;
    if (r >= R) return;

    float* myact = &act[wv][0][lane];

    const float o0 = orig[3*r+0], o1 = orig[3*r+1], o2 = orig[3*r+2];
    const float v0 = vec[3*r+0],  v1 = vec[3*r+1],  v2 = vec[3*r+2];

    float dist = BIGV;

    #pragma unroll 1
    for (int i = 0; i < NITER; ++i) {
        const float t1i = t1[(size_t)i * R + r];
        const float t2i = t2[(size_t)i * R + r];
        const int   mi  = mask[(size_t)i * R + r];
        if (!mi) continue;
        const float dt = t2i - t1i;

        const float io0 = fmaf(v0, t1i, o0);
        const float io1 = fmaf(v1, t1i, o1);
        const float io2 = fmaf(v2, t1i, o2);
        const float iv0 = v0 * dt, iv1 = v1 * dt, iv2 = v2 * dt;

        float a[DH];
        #pragma unroll
        for (int d = 0; d < DH; ++d) a[d] = 0.0f;

        #pragma unroll 1
        for (int p = 0; p < P; ++p) {
            const float tp = (float)p * (1.0f / 15.0f);
            const float x0 = fmaf(iv0, tp, io0) * INV_R;
            const float x1 = fmaf(iv1, tp, io1) * INV_R;
            const float x2 = fmaf(iv2, tp, io2) * INV_R;
            const f32x4* w0 = (const f32x4*)(win_l + (3*p+0)*DH);
            const f32x4* w1 = (const f32x4*)(win_l + (3*p+1)*DH);
            const f32x4* w2 = (const f32x4*)(win_l + (3*p+2)*DH);
            #pragma unroll
            for (int j = 0; j < 16; ++j) {
                const f32x4 u = w0[j], v4 = w1[j], w4 = w2[j];
                a[4*j+0] = fmaf(x2, w4.x, fmaf(x1, v4.x, fmaf(x0, u.x, a[4*j+0])));
                a[4*j+1] = fmaf(x2, w4.y, fmaf(x1, v4.y, fmaf(x0, u.y, a[4*j+1])));
                a[4*j+2] = fmaf(x2, w4.z, fmaf(x1, v4.z, fmaf(x0, u.z, a[4*j+2])));
                a[4*j+3] = fmaf(x2, w4.w, fmaf(x1, v4.w, fmaf(x0, u.w, a[4*j+3])));
            }
        }
        #pragma unroll
        for (int d = 0; d < DH; ++d) a[d] += b_in[d];

        float invprod = 1.0f;

        #pragma unroll 1
        for (int l = 0; l < NLAYER; ++l) {
            #pragma unroll
            for (int d = 0; d < DH; ++d) a[d] = fmaxf(a[d], 0.0f);

            float mu = 0.0f;
            #pragma unroll
            for (int d = 0; d < DH; ++d) mu += a[d];
            mu *= (1.0f / 64.0f);

            float var = 0.0f;
            #pragma unroll
            for (int d = 0; d < DH; ++d) {
                const float cdev = a[d] - mu;
                var = fmaf(cdev, cdev, var);
            }
            var *= (1.0f / 64.0f);
            const float inv = 1.0f / sqrtf(var + 1e-5f);
            invprod *= inv;

            const float* gp = ln_g + l*DH;
            const float* bp = ln_b + l*DH;

            #pragma unroll
            for (int d = 0; d < 32; ++d)
                myact[d*64] = fmaf((a[d] - mu) * inv, gp[d], bp[d]);
            float hh[32];
            #pragma unroll
            for (int j = 0; j < 32; ++j)
                hh[j] = fmaf((a[32+j] - mu) * inv, gp[32+j], bp[32+j]);

            #pragma unroll
            for (int d = 0; d < DH; ++d) a[d] = 0.0f;

            const float* Wl = wmid_l + l*DH*DH;
            #pragma unroll 4
            for (int k = 0; k < 32; ++k) {
                const float hk = myact[k*64];
                const f32x4* wr = (const f32x4*)(Wl + k*DH);
                #pragma unroll
                for (int j = 0; j < 16; ++j) {
                    const f32x4 w4 = wr[j];
                    a[4*j+0] = fmaf(hk, w4.x, a[4*j+0]);
                    a[4*j+1] = fmaf(hk, w4.y, a[4*j+1]);
                    a[4*j+2] = fmaf(hk, w4.z, a[4*j+2]);
                    a[4*j+3] = fmaf(hk, w4.w, a[4*j+3]);
                }
            }
            #pragma unroll
            for (int j = 0; j < 32; ++j)
                myact[j*64] = hh[j];
            #pragma unroll 4
            for (int k = 32; k < DH; ++k) {
                const float hk = myact[(k-32)*64];
                const f32x4* wr = (const f32x4*)(Wl + k*DH);
                #pragma unroll
                for (int j = 0; j < 16; ++j) {
                    const f32x4 w4 = wr[j];
                    a[4*j+0] = fmaf(hk, w4.x, a[4*j+0]);
                    a[4*j+1] = fmaf(hk, w4.y, a[4*j+1]);
                    a[4*j+2] = fmaf(hk, w4.z, a[4*j+2]);
                    a[4*j+3] = fmaf(hk, w4.w, a[4*j+3]);
                }
            }
            const float* bm = b_mid + l*DH;
            #pragma unroll
            for (int d = 0; d < DH; ++d) a[d] += bm[d];
        }

        #pragma unroll
        for (int d = 0; d < DH; ++d) a[d] = fmaxf(a[d], 0.0f);

        float c0 = 0.f, c1 = 0.f, c2 = 0.f, c3 = 0.f;
        float e0 = 0.f, e1 = 0.f, e2 = 0.f, e3 = 0.f;
        #pragma unroll
        for (int j = 0; j < 16; ++j) {
            c0 = fmaf(a[4*j+0], W_cls[4*j+0],  c0);
            c1 = fmaf(a[4*j+1], W_cls[4*j+1],  c1);
            c2 = fmaf(a[4*j+2], W_cls[4*j+2],  c2);
            c3 = fmaf(a[4*j+3], W_cls[4*j+3],  c3);
            e0 = fmaf(a[4*j+0], W_dist[4*j+0], e0);
            e1 = fmaf(a[4*j+1], W_dist[4*j+1], e1);
            e2 = fmaf(a[4*j+2], W_dist[4*j+2], e2);
            e3 = fmaf(a[4*j+3], W_dist[4*j+3], e3);
        }
        float cls = ((c0 + c1) + (c2 + c3)) + b_cls[0];
        float dv  = ((e0 + e1) + (e2 + e3)) + b_dist[0];
        float dval = fmaf(dv, dt, t1i);

        float thr = 2e-6f * invprod;
        thr = fminf(fmaxf(thr, 3e-5f), 2e-2f);
        if ((fabsf(cls) < thr) || (fabsf(dval) < thr)) {
            slow_eval(orig, vec, t1, t2, (size_t)i * R + r, (unsigned)r,
                      W_in, b_in, ln_g, ln_b, W_mid, b_mid,
                      W_cls, b_cls, W_dist, b_dist, cls, dval);
        }

        if (cls > 0.0f && dval < dist) dist = dval;
    }

    const float dfin = (dist == BIGV) ? 0.0f : dist;
    out[r]     = (dfin > 0.0f) ? 1.0f : 0.0f;
    out[R + r] = dfin;
}

extern "C" void kernel_launch(void* const* d_in, const int* in_sizes, int n_in,
                              void* d_out, int out_size, void* d_ws, size_t ws_size,
                              hipStream_t stream) {
    const float* orig   = (const float*)d_in[0];
    const float* vec    = (const float*)d_in[1];
    const float* t1     = (const float*)d_in[2];
    const float* t2     = (const float*)d_in[3];
    const int*   mask   = (const int*)  d_in[4];
    const float* W_in   = (const float*)d_in[5];
    const float* b_in   = (const float*)d_in[6];
    const float* ln_g   = (const float*)d_in[7];
    const float* ln_b   = (const float*)d_in[8];
    const float* W_mid  = (const float*)d_in[9];
    const float* b_mid  = (const float*)d_in[10];
    const float* W_cls  = (const float*)d_in[11];
    const float* b_cls  = (const float*)d_in[12];
    const float* W_dist = (const float*)d_in[13];
    const float* b_dist = (const float*)d_in[14];

    float* out = (float*)d_out;
    const int R = in_sizes[0] / 3;

    const size_t need_ws = 16 + 4ull * (size_t)R * NITER;
    const bool fast = (R == (1 << RLOG)) && (ws_size >= need_ws);

    if (fast) {
        unsigned* cnt   = (unsigned*)d_ws;
        unsigned* work  = (unsigned*)d_ws + 4;   // 16B offset
        unsigned* arena = (unsigned*)d_out + R;  // out[R..2R) as key arena

        hipMemsetAsync(cnt, 0, 4, stream);
        compact_k<<<(R * NITER) / 256, 256, 0, stream>>>(mask, cnt, work);
        init_k<<<1024, 256, 0, stream>>>(arena, R);
        main2_k<<<2048, 256, 0, stream>>>(orig, vec, t1, t2,
                                          W_in, b_in, ln_g, ln_b, W_mid, b_mid,
                                          W_cls, b_cls, W_dist, b_dist,
                                          work, cnt, arena);
        finalize_k<<<1024, 256, 0, stream>>>(out, R);
    } else {
        const int threads = 256;
        const int blocks  = (R + threads - 1) / threads;
        fallback_k<<<blocks, threads, 0, stream>>>(
            orig, vec, t1, t2, mask,
            W_in, b_in, ln_g, ln_b, W_mid, b_mid,
            W_cls, b_cls, W_dist, b_dist,
            out, R);
    }
}

// Round 14
// 5255.206 us; speedup vs baseline: 1.8619x; 1.2950x over previous
//
#include <hip/hip_runtime.h>
#include <math.h>

constexpr int   P      = 16;   // N_POINTS
constexpr int   DIN    = 48;   // P*3
constexpr int   DH     = 64;   // hidden dim
constexpr int   NITER  = 8;    // I
constexpr int   NLAYER = 2;    // L
constexpr float BIGV   = 1e9f;
constexpr float INV_R  = 1.0f / 2.5f;
constexpr int   RLOG   = 20;   // fast path requires R == 1<<20

typedef float f32x4 __attribute__((ext_vector_type(4)));
typedef const __attribute__((address_space(1))) f32x4 gf4_t;

// Launder a wave-uniform address onto the VMEM/vmcnt path (validated R4/R7/R8).
__device__ __forceinline__ gf4_t* vmem(const float* p) {
    unsigned long long a = (unsigned long long)p;
    asm volatile("" : "+v"(a));
    return (gf4_t*)a;
}

// monotonic float<->uint key map (total order)
__device__ __forceinline__ unsigned fkey(float f) {
    unsigned b = __float_as_uint(f);
    return (b & 0x80000000u) ? ~b : (b | 0x80000000u);
}
__device__ __forceinline__ float funkey(unsigned k) {
    unsigned b = (k & 0x80000000u) ? (k ^ 0x80000000u) : ~k;
    return __uint_as_float(b);
}

// ---------------------------------------------------------------------------
// SLOW PATH (rare): correctly-rounded f32 elementwise, f64 reductions.
// Verbatim from all passing rounds.
// ---------------------------------------------------------------------------
__device__ __noinline__
void slow_eval(const float* __restrict__ orig, const float* __restrict__ vec,
               const float* __restrict__ t1,   const float* __restrict__ t2,
               size_t tidx, unsigned r,
               const float* __restrict__ W_in,  const float* __restrict__ b_in,
               const float* __restrict__ ln_g,  const float* __restrict__ ln_b,
               const float* __restrict__ W_mid, const float* __restrict__ b_mid,
               const float* __restrict__ W_cls, const float* __restrict__ b_cls,
               const float* __restrict__ W_dist,const float* __restrict__ b_dist,
               float& cls_o, float& dval_o)
{
    const float o0 = orig[3*r+0], o1 = orig[3*r+1], o2 = orig[3*r+2];
    const float v0 = vec[3*r+0],  v1 = vec[3*r+1],  v2 = vec[3*r+2];
    const float t1i = t1[tidx], t2i = t2[tidx];

    const float dt  = __fsub_rn(t2i, t1i);
    const float io0 = __fadd_rn(o0, __fmul_rn(v0, t1i));
    const float io1 = __fadd_rn(o1, __fmul_rn(v1, t1i));
    const float io2 = __fadd_rn(o2, __fmul_rn(v2, t1i));
    const float iv0 = __fmul_rn(v0, dt);
    const float iv1 = __fmul_rn(v1, dt);
    const float iv2 = __fmul_rn(v2, dt);
    const float delta = 1.0f / 15.0f;

    float x[DIN];
    #pragma unroll
    for (int p = 0; p < P; ++p) {
        const float tp = __fmul_rn((float)p, delta);
        x[3*p+0] = __fdiv_rn(__fadd_rn(io0, __fmul_rn(iv0, tp)), 2.5f);
        x[3*p+1] = __fdiv_rn(__fadd_rn(io1, __fmul_rn(iv1, tp)), 2.5f);
        x[3*p+2] = __fdiv_rn(__fadd_rn(io2, __fmul_rn(iv2, tp)), 2.5f);
    }

    float a[DH];
    #pragma unroll 1
    for (int d = 0; d < DH; ++d) {
        double acc0 = 0.0, acc1 = 0.0;
        #pragma unroll
        for (int k = 0; k < DIN; k += 2) {
            acc0 = fma((double)x[k],   (double)W_in[k*DH + d],     acc0);
            acc1 = fma((double)x[k+1], (double)W_in[(k+1)*DH + d], acc1);
        }
        a[d] = __fadd_rn((float)(acc0 + acc1), b_in[d]);
    }

    #pragma unroll 1
    for (int l = 0; l < NLAYER; ++l) {
        #pragma unroll 1
        for (int d = 0; d < DH; ++d) a[d] = fmaxf(a[d], 0.0f);

        double s = 0.0;
        #pragma unroll 1
        for (int d = 0; d < DH; ++d) s += (double)a[d];
        const float mu = (float)(s * (1.0 / 64.0));

        double vs = 0.0;
        #pragma unroll 1
        for (int d = 0; d < DH; ++d) {
            const float c = __fsub_rn(a[d], mu);
            vs = fma((double)c, (double)c, vs);
        }
        const float var = (float)(vs * (1.0 / 64.0));
        const float ve  = __fadd_rn(var, 1e-5f);
        const float inv = (float)(1.0 / sqrt((double)ve));

        float hn[DH];
        #pragma unroll 1
        for (int d = 0; d < DH; ++d) {
            float t = __fsub_rn(a[d], mu);
            t = __fmul_rn(t, inv);
            t = __fmul_rn(t, ln_g[l*DH + d]);
            hn[d] = __fadd_rn(t, ln_b[l*DH + d]);
        }

        #pragma unroll 1
        for (int d = 0; d < DH; ++d) {
            double acc0 = 0.0, acc1 = 0.0;
            #pragma unroll
            for (int k = 0; k < DH; k += 2) {
                acc0 = fma((double)hn[k],   (double)W_mid[(l*DH + k)*DH + d],   acc0);
                acc1 = fma((double)hn[k+1], (double)W_mid[(l*DH + k+1)*DH + d], acc1);
            }
            a[d] = __fadd_rn((float)(acc0 + acc1), b_mid[l*DH + d]);
        }
    }

    double c0 = 0.0, c1 = 0.0, d0 = 0.0, d1 = 0.0;
    #pragma unroll 1
    for (int d = 0; d < DH; d += 2) {
        const float h0 = fmaxf(a[d],   0.0f);
        const float h1 = fmaxf(a[d+1], 0.0f);
        c0 = fma((double)h0, (double)W_cls[d],    c0);
        c1 = fma((double)h1, (double)W_cls[d+1],  c1);
        d0 = fma((double)h0, (double)W_dist[d],   d0);
        d1 = fma((double)h1, (double)W_dist[d+1], d1);
    }
    const float cls = __fadd_rn((float)(c0 + c1), b_cls[0]);
    const float dv  = __fadd_rn((float)(d0 + d1), b_dist[0]);
    cls_o  = cls;
    dval_o = __fadd_rn(__fmul_rn(dv, dt), t1i);
}

// ---------------------------------------------------------------------------
// Compaction: ONE atomic per 256-thread block (was: one per wave -> 131K
// serialized atomics on a single address ~= 1 ms). Worklist order changes;
// results don't (atomicMin is order-independent; slow-path decision per-item).
// ---------------------------------------------------------------------------
__global__ __launch_bounds__(256)
void compact_k(const int* __restrict__ mask, unsigned* __restrict__ cnt,
               unsigned* __restrict__ work)
{
    __shared__ unsigned wcnt[4];
    __shared__ unsigned woff[4];

    const int tid  = threadIdx.x;
    const int lane = tid & 63;
    const int wv   = tid >> 6;
    const int idx  = blockIdx.x * 256 + tid;

    const bool m = (mask[idx] != 0);
    const unsigned long long b = __ballot(m);
    const int nact = __popcll(b);
    if (lane == 0) wcnt[wv] = (unsigned)nact;
    __syncthreads();
    if (tid == 0) {
        const unsigned tot = wcnt[0] + wcnt[1] + wcnt[2] + wcnt[3];
        unsigned base = tot ? atomicAdd(cnt, tot) : 0u;
        #pragma unroll
        for (int w = 0; w < 4; ++w) { woff[w] = base; base += wcnt[w]; }
    }
    __syncthreads();
    if (m) {
        const int pre = __popcll(b & ((1ull << lane) - 1ull));
        work[woff[wv] + pre] = (unsigned)idx;
    }
}

__global__ __launch_bounds__(256)
void init_k(unsigned* __restrict__ arena, int R)
{
    const unsigned key_big = fkey(BIGV);
    for (int r = blockIdx.x * 256 + threadIdx.x; r < R; r += gridDim.x * 256)
        arena[r] = key_big;
}

__global__ __launch_bounds__(256)
void finalize_k(float* __restrict__ out, int R)
{
    unsigned* arena = (unsigned*)out + R;
    for (int r = blockIdx.x * 256 + threadIdx.x; r < R; r += gridDim.x * 256) {
        const float dist = funkey(arena[r]);
        const float dfin = (dist == BIGV) ? 0.0f : dist;
        out[r] = (dfin > 0.0f) ? 1.0f : 0.0f;
        ((float*)arena)[r] = dfin;
    }
}

// ---------------------------------------------------------------------------
// k-half matmul, 1 item per lane. Inner fmaf order identical to the
// validated R5/R13 body (k sequential, per component).
// ---------------------------------------------------------------------------
template<bool GLOBAL>
__device__ __forceinline__
void mm_khalf1(const float* Wbase, int kofs, const float* col, float (&a)[DH])
{
    #pragma unroll 2
    for (int k = 0; k < 32; ++k) {
        const float hk = col[k*64];
        if constexpr (GLOBAL) {
            gf4_t* wr = vmem(Wbase + (kofs + k)*DH);
            #pragma unroll
            for (int j = 0; j < 16; ++j) {
                const f32x4 w4 = wr[j];
                a[4*j+0] = fmaf(hk, w4.x, a[4*j+0]);
                a[4*j+1] = fmaf(hk, w4.y, a[4*j+1]);
                a[4*j+2] = fmaf(hk, w4.z, a[4*j+2]);
                a[4*j+3] = fmaf(hk, w4.w, a[4*j+3]);
            }
        } else {
            const f32x4* wr = (const f32x4*)(Wbase + (kofs + k)*DH);
            #pragma unroll
            for (int j = 0; j < 16; ++j) {
                const f32x4 w4 = wr[j];
                a[4*j+0] = fmaf(hk, w4.x, a[4*j+0]);
                a[4*j+1] = fmaf(hk, w4.y, a[4*j+1]);
                a[4*j+2] = fmaf(hk, w4.z, a[4*j+2]);
                a[4*j+3] = fmaf(hk, w4.w, a[4*j+3]);
            }
        }
    }
}

// ---------------------------------------------------------------------------
// MAIN: 256 threads (4 waves), ONE item/lane. __launch_bounds__(256, 3):
// VGPR cap 170 (live ~135 -> NO spill), LDS cap 53 KB -> act[4][32][64]
// (32 KB, stride-64 = 2-way bank alias, free) + W_mid layer-0 (16 KB) =
// 48 KB -> 3 blocks/CU = 12 waves/CU = 3 waves/SIMD (1.5x R13's TLP,
// first spill-free config above 2 waves/SIMD). W_in + W_mid layer-1 ride
// the vmcnt pipe (per-phase working set <=16 KB, L1-resident).
// Per-item FP sequence identical to validated R5/R13 (absmax 0.0039).
// ---------------------------------------------------------------------------
__global__ __launch_bounds__(256, 3)
void main1_k(const float* __restrict__ orig,
             const float* __restrict__ vec,
             const float* __restrict__ t1,
             const float* __restrict__ t2,
             const float* __restrict__ W_in,
             const float* __restrict__ b_in,
             const float* __restrict__ ln_g,
             const float* __restrict__ ln_b,
             const float* __restrict__ W_mid,
             const float* __restrict__ b_mid,
             const float* __restrict__ W_cls,
             const float* __restrict__ b_cls,
             const float* __restrict__ W_dist,
             const float* __restrict__ b_dist,
             const unsigned* __restrict__ work,
             const unsigned* __restrict__ cnt,
             unsigned* __restrict__ arena)
{
    __shared__ __align__(16) float wl0[DH*DH];      // 16 KiB: W_mid layer 0
    __shared__ __align__(16) float act[4][32][64];  // 32 KiB

    const int tid  = threadIdx.x;
    const int lane = tid & 63;
    const int wv   = tid >> 6;

    {   // stage W_mid layer 0 (whole block), one barrier
        f32x4*       dst = (f32x4*)wl0;
        const f32x4* s2  = (const f32x4*)W_mid;
        #pragma unroll 1
        for (int idx = tid; idx < DH*DH/4; idx += 256) dst[idx] = s2[idx];
    }
    __syncthreads();

    float* col = &act[wv][0][lane];   // element k lives at col[k*64]

    const unsigned T    = *cnt;
    const unsigned gtid = blockIdx.x * 256 + tid;
    const unsigned NTOT = gridDim.x * 256;

    for (unsigned g = gtid; g < T; g += NTOT) {
        const unsigned pk = work[g];
        const unsigned r  = pk & 0xFFFFFu;
        const float tt1 = t1[pk], tt2 = t2[pk];
        const float dt  = tt2 - tt1;
        const float o0 = orig[3*r+0], o1 = orig[3*r+1], o2 = orig[3*r+2];
        const float v0 = vec[3*r+0],  v1 = vec[3*r+1],  v2 = vec[3*r+2];
        const float io0 = fmaf(v0, tt1, o0);
        const float io1 = fmaf(v1, tt1, o1);
        const float io2 = fmaf(v2, tt1, o2);
        const float iv0 = v0 * dt, iv1 = v1 * dt, iv2 = v2 * dt;

        float a[DH];
        #pragma unroll
        for (int d = 0; d < DH; ++d) a[d] = 0.0f;

        // ---- input layer: x inline; W_in rows via vmcnt pipe (L1)
        #pragma unroll 1
        for (int p = 0; p < P; ++p) {
            const float tp = (float)p * (1.0f / 15.0f);
            const float x0 = fmaf(iv0, tp, io0) * INV_R;
            const float x1 = fmaf(iv1, tp, io1) * INV_R;
            const float x2 = fmaf(iv2, tp, io2) * INV_R;
            gf4_t* w0 = vmem(W_in + (3*p+0)*DH);
            gf4_t* w1 = vmem(W_in + (3*p+1)*DH);
            gf4_t* w2 = vmem(W_in + (3*p+2)*DH);
            #pragma unroll
            for (int j = 0; j < 16; ++j) {
                const f32x4 u = w0[j], v4 = w1[j], w4 = w2[j];
                a[4*j+0] = fmaf(x2, w4.x, fmaf(x1, v4.x, fmaf(x0, u.x, a[4*j+0])));
                a[4*j+1] = fmaf(x2, w4.y, fmaf(x1, v4.y, fmaf(x0, u.y, a[4*j+1])));
                a[4*j+2] = fmaf(x2, w4.z, fmaf(x1, v4.z, fmaf(x0, u.z, a[4*j+2])));
                a[4*j+3] = fmaf(x2, w4.w, fmaf(x1, v4.w, fmaf(x0, u.w, a[4*j+3])));
            }
        }
        #pragma unroll
        for (int d = 0; d < DH; ++d) a[d] += b_in[d];

        float invprod = 1.0f;

        // ---- mid layers: relu -> LN -> k-halved matmul
        // layer 0 weights: LDS (wl0). layer 1 weights: vmem (L1/L2).
        #pragma unroll
        for (int l = 0; l < NLAYER; ++l) {
            #pragma unroll
            for (int d = 0; d < DH; ++d) a[d] = fmaxf(a[d], 0.0f);

            float mu = 0.0f;
            #pragma unroll
            for (int d = 0; d < DH; ++d) mu += a[d];
            mu *= (1.0f / 64.0f);

            float var = 0.0f;
            #pragma unroll
            for (int d = 0; d < DH; ++d) {
                const float c = a[d] - mu;
                var = fmaf(c, c, var);
            }
            var *= (1.0f / 64.0f);
            const float inv = 1.0f / sqrtf(var + 1e-5f);
            invprod *= inv;

            const float* gg = ln_g + l*DH;
            const float* bb = ln_b + l*DH;

            // lower half of hn -> LDS column; upper half -> 32 temp regs
            #pragma unroll
            for (int d = 0; d < 32; ++d)
                col[d*64] = fmaf((a[d] - mu) * inv, gg[d], bb[d]);
            float hh[32];
            #pragma unroll
            for (int j = 0; j < 32; ++j)
                hh[j] = fmaf((a[32+j] - mu) * inv, gg[32+j], bb[32+j]);

            #pragma unroll
            for (int d = 0; d < DH; ++d) a[d] = 0.0f;

            if (l == 0) mm_khalf1<false>(wl0,            0, col, a);
            else        mm_khalf1<true >(W_mid + DH*DH,  0, col, a);

            #pragma unroll
            for (int j = 0; j < 32; ++j)    // park upper half (in-order DS)
                col[j*64] = hh[j];

            if (l == 0) mm_khalf1<false>(wl0,           32, col, a);
            else        mm_khalf1<true >(W_mid + DH*DH, 32, col, a);

            const float* bm = b_mid + l*DH;
            #pragma unroll
            for (int d = 0; d < DH; ++d) a[d] += bm[d];
        }

        // ---- heads (4 chains each, identical to validated rounds)
        #pragma unroll
        for (int d = 0; d < DH; ++d) a[d] = fmaxf(a[d], 0.0f);

        float c0 = 0.f, c1 = 0.f, c2 = 0.f, c3 = 0.f;
        float e0 = 0.f, e1 = 0.f, e2 = 0.f, e3 = 0.f;
        #pragma unroll
        for (int j = 0; j < 16; ++j) {
            c0 = fmaf(a[4*j+0], W_cls[4*j+0],  c0);
            c1 = fmaf(a[4*j+1], W_cls[4*j+1],  c1);
            c2 = fmaf(a[4*j+2], W_cls[4*j+2],  c2);
            c3 = fmaf(a[4*j+3], W_cls[4*j+3],  c3);
            e0 = fmaf(a[4*j+0], W_dist[4*j+0], e0);
            e1 = fmaf(a[4*j+1], W_dist[4*j+1], e1);
            e2 = fmaf(a[4*j+2], W_dist[4*j+2], e2);
            e3 = fmaf(a[4*j+3], W_dist[4*j+3], e3);
        }
        float cls = ((c0 + c1) + (c2 + c3)) + b_cls[0];
        float dv  = ((e0 + e1) + (e2 + e3)) + b_dist[0];
        float dval = fmaf(dv, dt, tt1);

        float thr = 2e-6f * invprod;
        thr = fminf(fmaxf(thr, 3e-5f), 2e-2f);
        if ((fabsf(cls) < thr) || (fabsf(dval) < thr)) {
            slow_eval(orig, vec, t1, t2, (size_t)pk, r,
                      W_in, b_in, ln_g, ln_b, W_mid, b_mid,
                      W_cls, b_cls, W_dist, b_dist, cls, dval);
        }
        if (cls > 0.0f)
            atomicMin(arena + r, fkey(dval));
    }
}

// ---------------------------------------------------------------------------
// FALLBACK (round-5 kernel, known-good) for unexpected R / small workspace.
// ---------------------------------------------------------------------------
__global__ __launch_bounds__(256, 2)
void fallback_k(const float* __restrict__ orig, const float* __restrict__ vec,
                const float* __restrict__ t1,   const float* __restrict__ t2,
                const int*   __restrict__ mask,
                const float* __restrict__ W_in,  const float* __restrict__ b_in,
                const float* __restrict__ ln_g,  const float* __restrict__ ln_b,
                const float* __restrict__ W_mid, const float* __restrict__ b_mid,
                const float* __restrict__ W_cls, const float* __restrict__ b_cls,
                const float* __restrict__ W_dist,const float* __restrict__ b_dist,
                float* __restrict__ out, int R)
{
    __shared__ __align__(16) float wlds[DIN*DH + NLAYER*DH*DH];
    __shared__ __align__(16) float act[4][32][64];

    const int tid  = threadIdx.x;
    const int lane = tid & 63;
    const int wv   = tid >> 6;

    {
        f32x4*       dst = (f32x4*)wlds;
        const f32x4* s1  = (const f32x4*)W_in;
        const f32x4* s2  = (const f32x4*)W_mid;
        #pragma unroll 1
        for (int idx = tid; idx < DIN*DH/4; idx += 256)        dst[idx] = s1[idx];
        #pragma unroll 1
        for (int idx = tid; idx < NLAYER*DH*DH/4; idx += 256)  dst[DIN*DH/4 + idx] = s2[idx];
    }
    __syncthreads();

    const float* win_l  = wlds;
    const float* wmid_l = wlds + DIN*DH;

    const int r = blockIdx.x * 256 + tid;
    if (r >= R) return;

    float* myact = &act[wv][0][lane];

    const float o0 = orig[3*r+0], o1 = orig[3*r+1], o2 = orig[3*r+2];
    const float v0 = vec[3*r+0],  v1 = vec[3*r+1],  v2 = vec[3*r+2];

    float dist = BIGV;

    #pragma unroll 1
    for (int i = 0; i < NITER; ++i) {
        const float t1i = t1[(size_t)i * R + r];
        const float t2i = t2[(size_t)i * R + r];
        const int   mi  = mask[(size_t)i * R + r];
        if (!mi) continue;
        const float dt = t2i - t1i;

        const float io0 = fmaf(v0, t1i, o0);
        const float io1 = fmaf(v1, t1i, o1);
        const float io2 = fmaf(v2, t1i, o2);
        const float iv0 = v0 * dt, iv1 = v1 * dt, iv2 = v2 * dt;

        float a[DH];
        #pragma unroll
        for (int d = 0; d < DH; ++d) a[d] = 0.0f;

        #pragma unroll 1
        for (int p = 0; p < P; ++p) {
            const float tp = (float)p * (1.0f / 15.0f);
            const float x0 = fmaf(iv0, tp, io0) * INV_R;
            const float x1 = fmaf(iv1, tp, io1) * INV_R;
            const float x2 = fmaf(iv2, tp, io2) * INV_R;
            const f32x4* w0 = (const f32x4*)(win_l + (3*p+0)*DH);
            const f32x4* w1 = (const f32x4*)(win_l + (3*p+1)*DH);
            const f32x4* w2 = (const f32x4*)(win_l + (3*p+2)*DH);
            #pragma unroll
            for (int j = 0; j < 16; ++j) {
                const f32x4 u = w0[j], v4 = w1[j], w4 = w2[j];
                a[4*j+0] = fmaf(x2, w4.x, fmaf(x1, v4.x, fmaf(x0, u.x, a[4*j+0])));
                a[4*j+1] = fmaf(x2, w4.y, fmaf(x1, v4.y, fmaf(x0, u.y, a[4*j+1])));
                a[4*j+2] = fmaf(x2, w4.z, fmaf(x1, v4.z, fmaf(x0, u.z, a[4*j+2])));
                a[4*j+3] = fmaf(x2, w4.w, fmaf(x1, v4.w, fmaf(x0, u.w, a[4*j+3])));
            }
        }
        #pragma unroll
        for (int d = 0; d < DH; ++d) a[d] += b_in[d];

        float invprod = 1.0f;

        #pragma unroll 1
        for (int l = 0; l < NLAYER; ++l) {
            #pragma unroll
            for (int d = 0; d < DH; ++d) a[d] = fmaxf(a[d], 0.0f);

            float mu = 0.0f;
            #pragma unroll
            for (int d = 0; d < DH; ++d) mu += a[d];
            mu *= (1.0f / 64.0f);

            float var = 0.0f;
            #pragma unroll
            for (int d = 0; d < DH; ++d) {
                const float cdev = a[d] - mu;
                var = fmaf(cdev, cdev, var);
            }
            var *= (1.0f / 64.0f);
            const float inv = 1.0f / sqrtf(var + 1e-5f);
            invprod *= inv;

            const float* gp = ln_g + l*DH;
            const float* bp = ln_b + l*DH;

            #pragma unroll
            for (int d = 0; d < 32; ++d)
                myact[d*64] = fmaf((a[d] - mu) * inv, gp[d], bp[d]);
            float hh[32];
            #pragma unroll
            for (int j = 0; j < 32; ++j)
                hh[j] = fmaf((a[32+j] - mu) * inv, gp[32+j], bp[32+j]);

            #pragma unroll
            for (int d = 0; d < DH; ++d) a[d] = 0.0f;

            const float* Wl = wmid_l + l*DH*DH;
            #pragma unroll 4
            for (int k = 0; k < 32; ++k) {
                const float hk = myact[k*64];
                const f32x4* wr = (const f32x4*)(Wl + k*DH);
                #pragma unroll
                for (int j = 0; j < 16; ++j) {
                    const f32x4 w4 = wr[j];
                    a[4*j+0] = fmaf(hk, w4.x, a[4*j+0]);
                    a[4*j+1] = fmaf(hk, w4.y, a[4*j+1]);
                    a[4*j+2] = fmaf(hk, w4.z, a[4*j+2]);
                    a[4*j+3] = fmaf(hk, w4.w, a[4*j+3]);
                }
            }
            #pragma unroll
            for (int j = 0; j < 32; ++j)
                myact[j*64] = hh[j];
            #pragma unroll 4
            for (int k = 32; k < DH; ++k) {
                const float hk = myact[(k-32)*64];
                const f32x4* wr = (const f32x4*)(Wl + k*DH);
                #pragma unroll
                for (int j = 0; j < 16; ++j) {
                    const f32x4 w4 = wr[j];
                    a[4*j+0] = fmaf(hk, w4.x, a[4*j+0]);
                    a[4*j+1] = fmaf(hk, w4.y, a[4*j+1]);
                    a[4*j+2] = fmaf(hk, w4.z, a[4*j+2]);
                    a[4*j+3] = fmaf(hk, w4.w, a[4*j+3]);
                }
            }
            const float* bm = b_mid + l*DH;
            #pragma unroll
            for (int d = 0; d < DH; ++d) a[d] += bm[d];
        }

        #pragma unroll
        for (int d = 0; d < DH; ++d) a[d] = fmaxf(a[d], 0.0f);

        float c0 = 0.f, c1 = 0.f, c2 = 0.f, c3 = 0.f;
        float e0 = 0.f, e1 = 0.f, e2 = 0.f, e3 = 0.f;
        #pragma unroll
        for (int j = 0; j < 16; ++j) {
            c0 = fmaf(a[4*j+0], W_cls[4*j+0],  c0);
            c1 = fmaf(a[4*j+1], W_cls[4*j+1],  c1);
            c2 = fmaf(a[4*j+2], W_cls[4*j+2],  c2);
            c3 = fmaf(a[4*j+3], W_cls[4*j+3],  c3);
            e0 = fmaf(a[4*j+0], W_dist[4*j+0], e0);
            e1 = fmaf(a[4*j+1], W_dist[4*j+1], e1);
            e2 = fmaf(a[4*j+2], W_dist[4*j+2], e2);
            e3 = fmaf(a[4*j+3], W_dist[4*j+3], e3);
        }
        float cls = ((c0 + c1) + (c2 + c3)) + b_cls[0];
        float dv  = ((e0 + e1) + (e2 + e3)) + b_dist[0];
        float dval = fmaf(dv, dt, t1i);

        float thr = 2e-6f * invprod;
        thr = fminf(fmaxf(thr, 3e-5f), 2e-2f);
        if ((fabsf(cls) < thr) || (fabsf(dval) < thr)) {
            slow_eval(orig, vec, t1, t2, (size_t)i * R + r, (unsigned)r,
                      W_in, b_in, ln_g, ln_b, W_mid, b_mid,
                      W_cls, b_cls, W_dist, b_dist, cls, dval);
        }

        if (cls > 0.0f && dval < dist) dist = dval;
    }

    const float dfin = (dist == BIGV) ? 0.0f : dist;
    out[r]     = (dfin > 0.0f) ? 1.0f : 0.0f;
    out[R + r] = dfin;
}

extern "C" void kernel_launch(void* const* d_in, const int* in_sizes, int n_in,
                              void* d_out, int out_size, void* d_ws, size_t ws_size,
                              hipStream_t stream) {
    const float* orig   = (const float*)d_in[0];
    const float* vec    = (const float*)d_in[1];
    const float* t1     = (const float*)d_in[2];
    const float* t2     = (const float*)d_in[3];
    const int*   mask   = (const int*)  d_in[4];
    const float* W_in   = (const float*)d_in[5];
    const float* b_in   = (const float*)d_in[6];
    const float* ln_g   = (const float*)d_in[7];
    const float* ln_b   = (const float*)d_in[8];
    const float* W_mid  = (const float*)d_in[9];
    const float* b_mid  = (const float*)d_in[10];
    const float* W_cls  = (const float*)d_in[11];
    const float* b_cls  = (const float*)d_in[12];
    const float* W_dist = (const float*)d_in[13];
    const float* b_dist = (const float*)d_in[14];

    float* out = (float*)d_out;
    const int R = in_sizes[0] / 3;

    const size_t need_ws = 16 + 4ull * (size_t)R * NITER;
    const bool fast = (R == (1 << RLOG)) && (ws_size >= need_ws);

    if (fast) {
        unsigned* cnt   = (unsigned*)d_ws;
        unsigned* work  = (unsigned*)d_ws + 4;   // 16B offset
        unsigned* arena = (unsigned*)d_out + R;  // out[R..2R) as key arena

        hipMemsetAsync(cnt, 0, 4, stream);
        compact_k<<<(R * NITER) / 256, 256, 0, stream>>>(mask, cnt, work);
        init_k<<<1024, 256, 0, stream>>>(arena, R);
        main1_k<<<4096, 256, 0, stream>>>(orig, vec, t1, t2,
                                          W_in, b_in, ln_g, ln_b, W_mid, b_mid,
                                          W_cls, b_cls, W_dist, b_dist,
                                          work, cnt, arena);
        finalize_k<<<1024, 256, 0, stream>>>(out, R);
    } else {
        const int threads = 256;
        const int blocks  = (R + threads - 1) / threads;
        fallback_k<<<blocks, threads, 0, stream>>>(
            orig, vec, t1, t2, mask,
            W_in, b_in, ln_g, ln_b, W_mid, b_mid,
            W_cls, b_cls, W_dist, b_dist,
            out, R);
    }
}